// Round 6
// baseline (11145.192 us; speedup 1.0000x reference)
//
#include <hip/hip_runtime.h>
#include <math.h>

#define NN 2000
#define BB 32
#define TT 24
#define T_OUT 12
#define HH 64
#define DD 10
#define NP 2048   // padded node dim
#define BC 2048   // B*H columns (j = b*64 + c)

typedef unsigned short ushort_t;
typedef __bf16 bf16x8 __attribute__((ext_vector_type(8)));
typedef float f32x4 __attribute__((ext_vector_type(4)));

__device__ __forceinline__ float sigmoidf_(float x) { return 1.f / (1.f + expf(-x)); }

__device__ __forceinline__ ushort_t f2bf(float f) {
    unsigned int u = __float_as_uint(f);
    unsigned int r = (u + 0x7FFFu + ((u >> 16) & 1u)) >> 16;
    return (ushort_t)r;
}
__device__ __forceinline__ float bf2f(ushort_t s) {
    return __uint_as_float(((unsigned int)s) << 16);
}

__device__ __forceinline__ void glld16(const ushort_t* g, ushort_t* lds) {
    __builtin_amdgcn_global_load_lds(
        (const __attribute__((address_space(1))) char*)g,
        (__attribute__((address_space(3))) char*)lds, 16, 0, 0);
}

// ---------------- workspace layout (bytes), high-water 122,896,384 ----------------
constexpr size_t SZ_NPNP2 = (size_t)NP * NP * 2;   // 8,388,608
constexpr size_t SZ_ST4   = (size_t)NN * BC * 4;   // 16,384,000
constexpr size_t SZ_ST2   = (size_t)NN * BC * 2;   // 8,192,000

constexpr size_t ABF_OFF  = 0;
constexpr size_t H1T_OFF  = ABF_OFF + SZ_NPNP2;
constexpr size_t TMPT_OFF = H1T_OFF + SZ_NPNP2;
constexpr size_t H0F_OFF  = TMPT_OFF + SZ_NPNP2;
constexpr size_t H1F_OFF  = H0F_OFF + SZ_ST4;
constexpr size_t ZF_OFF   = H1F_OFF + SZ_ST4;       // f32; overlaid with A_f32 in setup
constexpr size_t H0B_OFF  = ZF_OFF + SZ_ST4;
constexpr size_t H1B_OFF  = H0B_OFF + SZ_ST2;
constexpr size_t RHB_OFF  = H1B_OFF + SZ_ST2;
constexpr size_t AH0_OFF  = RHB_OFF + SZ_ST2;
constexpr size_t AHX_OFF  = AH0_OFF + SZ_ST2;       // shared: Arh0 / Ah1 / Arh1
constexpr size_t AXF_OFF  = AHX_OFF + SZ_ST2;       // [B][T][N] f32
constexpr size_t BTG0_OFF = AXF_OFF + (size_t)BB * TT * NN * 4;
constexpr size_t BTC0_OFF = BTG0_OFF + (size_t)DD * 128 * 128 * 2;  // 327,680
constexpr size_t BTG1_OFF = BTC0_OFF + (size_t)DD * 64 * 128 * 2;   // 163,840
constexpr size_t BTC1_OFF = BTG1_OFF + (size_t)DD * 128 * 256 * 2;  // 655,360
constexpr size_t WS_TOP   = BTC1_OFF + (size_t)DD * 64 * 256 * 2;   // 122,896,384

// ---------------- A_f32 = row_softmax(relu(E E^T)) ----------------
__global__ __launch_bounds__(256) void compute_A_kernel(const float* __restrict__ E,
                                                        float* __restrict__ A) {
    const int row = blockIdx.x;
    const int tid = threadIdx.x;
    float er[DD];
#pragma unroll
    for (int d = 0; d < DD; ++d) er[d] = E[row * DD + d];
    __shared__ float red[8];

    float lmax = -1e30f;
    for (int c = tid; c < NN; c += 256) {
        float s = 0.f;
#pragma unroll
        for (int d = 0; d < DD; ++d) s += er[d] * E[c * DD + d];
        s = fmaxf(s, 0.f);
        A[(size_t)row * NN + c] = s;
        lmax = fmaxf(lmax, s);
    }
#pragma unroll
    for (int o = 32; o > 0; o >>= 1) lmax = fmaxf(lmax, __shfl_down(lmax, o, 64));
    if ((tid & 63) == 0) red[tid >> 6] = lmax;
    __syncthreads();
    const float rmax = fmaxf(fmaxf(red[0], red[1]), fmaxf(red[2], red[3]));
    __syncthreads();

    float lsum = 0.f;
    for (int c = tid; c < NN; c += 256) {
        float v = expf(A[(size_t)row * NN + c] - rmax);
        A[(size_t)row * NN + c] = v;
        lsum += v;
    }
#pragma unroll
    for (int o = 32; o > 0; o >>= 1) lsum += __shfl_down(lsum, o, 64);
    if ((tid & 63) == 0) red[4 + (tid >> 6)] = lsum;
    __syncthreads();
    const float inv = 1.f / (red[4] + red[5] + red[6] + red[7]);
    for (int c = tid; c < NN; c += 256) A[(size_t)row * NN + c] *= inv;
}

// ---------------- A_f32 -> A_bf [2048][2048] with zero pad ----------------
__global__ __launch_bounds__(256) void convert_A(const float* __restrict__ Af,
                                                 ushort_t* __restrict__ Ab) {
    size_t idx = (size_t)blockIdx.x * 256 + threadIdx.x;
    int r = (int)(idx >> 11), c = (int)(idx & 2047);
    float v = (r < NN && c < NN) ? Af[(size_t)r * NN + c] : 0.f;
    Ab[idx] = f2bf(v);
}

// ---------------- Ax[b,t,n] = sum_m A[n,m] x[b,t,m]  (f32, one-time) ----------------
__global__ __launch_bounds__(256) void ax_kernel(const float* __restrict__ A,
                                                 const float* __restrict__ x,
                                                 float* __restrict__ Ax) {
    __shared__ float As[64][65];
    __shared__ float xs[64][25];
    const int n0 = blockIdx.x * 64;
    const int b = blockIdx.y;
    const int tid = threadIdx.x;
    float acc[6] = {0, 0, 0, 0, 0, 0};
    for (int m0 = 0; m0 < NN; m0 += 64) {
#pragma unroll
        for (int l = 0; l < 16; ++l) {
            int idx = tid + l * 256;
            int r = idx >> 6, c = idx & 63;
            int n = n0 + r, m = m0 + c;
            As[r][c] = (n < NN && m < NN) ? A[(size_t)n * NN + m] : 0.f;
        }
        for (int idx = tid; idx < 64 * TT; idx += 256) {
            int c = idx >> 6, r = idx & 63;
            int m = m0 + r;
            xs[r][c] = (m < NN) ? x[((size_t)b * TT + c) * NN + m] : 0.f;
        }
        __syncthreads();
#pragma unroll 4
        for (int mm = 0; mm < 64; ++mm) {
#pragma unroll
            for (int j = 0; j < 6; ++j) {
                int oi = tid + j * 256;
                int r = oi / TT, c = oi % TT;
                acc[j] += As[r][mm] * xs[mm][c];
            }
        }
        __syncthreads();
    }
#pragma unroll
    for (int j = 0; j < 6; ++j) {
        int oi = tid + j * 256;
        int r = oi / TT, c = oi % TT;
        int n = n0 + r;
        if (n < NN) Ax[((size_t)b * TT + c) * NN + n] = acc[j];
    }
}

// ---------------- transpose bf16 [n][j] -> [j][n], zero-fill n>=NN ----------------
__global__ __launch_bounds__(256) void transpose_bf(const ushort_t* __restrict__ src,
                                                    ushort_t* __restrict__ dst) {
    __shared__ ushort_t tile[64][65];
    const int jb = blockIdx.x * 64, nb = blockIdx.y * 64;
    const int tid = threadIdx.x;
#pragma unroll
    for (int l = 0; l < 16; ++l) {
        int idx = tid + l * 256;
        int r = idx >> 6, c = idx & 63;  // r: n-local, c: j-local
        int n = nb + r;
        tile[r][c] = (n < NN) ? src[(size_t)n * BC + jb + c] : (ushort_t)0;
    }
    __syncthreads();
#pragma unroll
    for (int l = 0; l < 16; ++l) {
        int idx = tid + l * 256;
        int r = idx >> 6, c = idx & 63;  // r: j-local, c: n-local
        dst[(size_t)(jb + r) * NP + nb + c] = tile[c][r];
    }
}

// ---------------- MFMA GEMM: Y[n][j] = sum_m A[n][m] * XT[j][m], bf16 ----------------
// 64x128 tile, BK=64, 4 waves (col-split), 512 blocks, XCD-chunked swizzle.
__global__ __launch_bounds__(256) void gemm_mfma(const ushort_t* __restrict__ Ab,
                                                 const ushort_t* __restrict__ XT,
                                                 ushort_t* __restrict__ Y) {
    __shared__ __align__(16) ushort_t As[64 * 64];
    __shared__ __align__(16) ushort_t Bs[128 * 64];
    const int tid = threadIdx.x;
    const int w = tid >> 6, l = tid & 63, lr = l & 15, lg = l >> 4;
    // bijective XCD swizzle: 512 blocks, 512 % 8 == 0
    const int o = blockIdx.y * 32 + blockIdx.x;
    const int wg = (o & 7) * 64 + (o >> 3);
    const int n0 = (wg & 31) * 64, j0 = (wg >> 5) * 128;
    f32x4 acc[4][2] = {};

    for (int ks = 0; ks < NP / 64; ++ks) {
        const int k0 = ks * 64;
#pragma unroll
        for (int p = 0; p < 2; ++p) {  // A tile: 64 rows x 64 k
            const int idx = p * 256 + tid;
            const int row = idx >> 3, sl = idx & 7;
            glld16(Ab + (size_t)(n0 + row) * NP + k0 + ((sl ^ (row & 7)) << 3),
                   (ushort_t*)((char*)As + idx * 16));
        }
#pragma unroll
        for (int p = 0; p < 4; ++p) {  // B tile: 128 rows x 64 k
            const int idx = p * 256 + tid;
            const int row = idx >> 3, sl = idx & 7;
            glld16(XT + (size_t)(j0 + row) * NP + k0 + ((sl ^ (row & 7)) << 3),
                   (ushort_t*)((char*)Bs + idx * 16));
        }
        __syncthreads();

        bf16x8 av[2][4], bv[2][2];
#pragma unroll
        for (int kk = 0; kk < 2; ++kk) {
#pragma unroll
            for (int m = 0; m < 4; ++m) {
                const int rr = m * 16 + lr;
                av[kk][m] = *(const bf16x8*)&As[rr * 64 + (((kk * 4 + lg) ^ (rr & 7)) << 3)];
            }
#pragma unroll
            for (int nt = 0; nt < 2; ++nt) {
                const int br = w * 32 + nt * 16 + lr;
                bv[kk][nt] = *(const bf16x8*)&Bs[br * 64 + (((kk * 4 + lg) ^ (br & 7)) << 3)];
            }
        }
#pragma unroll
        for (int kk = 0; kk < 2; ++kk)
#pragma unroll
            for (int m = 0; m < 4; ++m)
#pragma unroll
                for (int nt = 0; nt < 2; ++nt)
                    acc[m][nt] = __builtin_amdgcn_mfma_f32_16x16x32_bf16(av[kk][m], bv[kk][nt], acc[m][nt], 0, 0, 0);
        __syncthreads();
    }

#pragma unroll
    for (int m = 0; m < 4; ++m)
#pragma unroll
        for (int r = 0; r < 4; ++r) {
            const int n = n0 + m * 16 + lg * 4 + r;
            if (n < NN) {
#pragma unroll
                for (int nt = 0; nt < 2; ++nt)
                    Y[(size_t)n * BC + j0 + w * 32 + nt * 16 + lr] = f2bf(acc[m][nt][r]);
            }
        }
}

// ---------------- prep: Bt[d][o][K] bf16 from pool (B^T form for MFMA) ----------------
// L0: K=128, k -> (kk=k>>6, i=1+(k&63)).  L1: K=256, s=k>>6 -> (kk=s&1, i=(s>>1)*64+(k&63)).
template <int CI, int CO, bool L0>
__global__ __launch_bounds__(256) void prepW(const float* __restrict__ Wp,
                                             ushort_t* __restrict__ Bt) {
    constexpr int K = L0 ? 128 : 256;
    const int idx = blockIdx.x * 256 + threadIdx.x;
    if (idx >= DD * CO * K) return;
    const int d = idx / (CO * K);
    const int rem = idx - d * CO * K;
    const int o = rem / K;
    const int k = rem - o * K;
    const int s = k >> 6, c = k & 63;
    const int kk = L0 ? s : (s & 1);
    const int i = L0 ? (1 + c) : ((s >> 1) * 64 + c);
    Bt[idx] = f2bf(Wp[((size_t)(d * 2 + kk) * CI + i) * CO + o]);
}

// ---------------- factored-MFMA NAPL gconv, v3: no LDS, reg-hoisted A-frags ----------------
// Block = 64 output rows j (= 2 nodes x 32 batches). out[j,o] = sum_d e[n,d]*(in @ Wp[d])[j,o].
// Linearity: OUT = sum_half sum_d e_d * P_{half,d} -> hoist each K-half's 16 A-frags to VGPRs,
// reuse across the d-loop. A-frags loaded directly from global (L2); B-frags stream from tiny
// Bt pools (L2). No barriers.
// GATE (CO=128): o<64 -> z=sigma -> zf ; o>=64 -> rh = sigma*hf -> outb.
// CAND (CO=64): h_new = z*hf + (1-z)*tanh(val) -> outf (f32) + outb (bf16).
template <int NSEGS, int CO, bool GATE, bool HASX>
__global__ __launch_bounds__(256) void napl2(
    const ushort_t* __restrict__ Bt, const float* __restrict__ bp,
    const float* __restrict__ emb, const float* __restrict__ WxPool,
    const ushort_t* __restrict__ s0p, const ushort_t* __restrict__ s1p,
    const ushort_t* __restrict__ s2p, const ushort_t* __restrict__ s3p,
    const float* __restrict__ xv, const float* __restrict__ axv,
    const float* hf, float* __restrict__ zf,
    ushort_t* __restrict__ outb, float* outf, int t) {
    constexpr int K = NSEGS * 64;
    constexpr int NT = (CO == 128) ? 2 : 1;
    constexpr int NHALF = NSEGS / 2;
    const int tid = threadIdx.x;
    const int w = tid >> 6, l = tid & 63, lr = l & 15, lg = l >> 4;
    const int n0 = blockIdx.x * 2;
    const int ob = w * (16 * NT);
    const ushort_t* segs[4] = {s0p, s1p, s2p, s3p};

    // per-node embeddings (block-uniform addresses -> SGPRs)
    float e0[DD], e1[DD];
#pragma unroll
    for (int d = 0; d < DD; ++d) {
        e0[d] = emb[n0 * DD + d];
        e1[d] = emb[(n0 + 1) * DD + d];
    }

    f32x4 OUT[4][NT] = {};
#pragma unroll 1
    for (int hfI = 0; hfI < NHALF; ++hfI) {
        // hoist this half's 16 A-fragments into registers (read once, reuse x10 d's)
        bf16x8 av[4][4];
#pragma unroll
        for (int c = 0; c < 4; ++c) {
            const int s = hfI * 2 + (c >> 1);
            const int kin = (c & 1) * 32 + lg * 8;
            const ushort_t* sp = segs[s];
#pragma unroll
            for (int m = 0; m < 4; ++m) {
                const int jl = m * 16 + lr;
                av[c][m] = *(const bf16x8*)&sp[(size_t)(n0 + (jl >> 5)) * BC + (jl & 31) * 64 + kin];
            }
        }
#pragma unroll 2
        for (int d = 0; d < DD; ++d) {
            const ushort_t* btd = Bt + (size_t)d * CO * K;
            f32x4 P[4][NT] = {};
#pragma unroll
            for (int c = 0; c < 4; ++c) {
                const int kg = (hfI * 2 + (c >> 1)) * 64 + (c & 1) * 32 + lg * 8;
                bf16x8 bv[NT];
#pragma unroll
                for (int nt = 0; nt < NT; ++nt)
                    bv[nt] = *(const bf16x8*)&btd[(size_t)(ob + nt * 16 + lr) * K + kg];
#pragma unroll
                for (int m = 0; m < 4; ++m)
#pragma unroll
                    for (int nt = 0; nt < NT; ++nt)
                        P[m][nt] = __builtin_amdgcn_mfma_f32_16x16x32_bf16(av[c][m], bv[nt], P[m][nt], 0, 0, 0);
            }
#pragma unroll
            for (int m = 0; m < 4; ++m) {
                const float e = (m < 2) ? e0[d] : e1[d];
#pragma unroll
                for (int nt = 0; nt < NT; ++nt)
#pragma unroll
                    for (int r = 0; r < 4; ++r)
                        OUT[m][nt][r] += e * P[m][nt][r];
            }
        }
    }

    // per-node bias and (optional) x rank-2 weights
    float bias[2][NT];
#pragma unroll
    for (int nd = 0; nd < 2; ++nd)
#pragma unroll
        for (int nt = 0; nt < NT; ++nt) {
            float s_ = 0.f;
#pragma unroll
            for (int d = 0; d < DD; ++d)
                s_ += ((nd == 0) ? e0[d] : e1[d]) * bp[d * CO + ob + nt * 16 + lr];
            bias[nd][nt] = s_;
        }
    float wx[2][2][NT] = {};
    if (HASX) {
#pragma unroll
        for (int kk = 0; kk < 2; ++kk)
#pragma unroll
            for (int nd = 0; nd < 2; ++nd)
#pragma unroll
                for (int nt = 0; nt < NT; ++nt) {
                    float s_ = 0.f;
#pragma unroll
                    for (int d = 0; d < DD; ++d)
                        s_ += ((nd == 0) ? e0[d] : e1[d]) *
                              WxPool[(size_t)(d * 2 + kk) * 65 * CO + ob + nt * 16 + lr];
                    wx[kk][nd][nt] = s_;
                }
    }

#pragma unroll
    for (int m = 0; m < 4; ++m) {
        const int nd = m >> 1;
        const int n = n0 + nd;
#pragma unroll
        for (int r = 0; r < 4; ++r) {
            const int row = m * 16 + lg * 4 + r;
            const int b = row & 31;
            const size_t nb = (size_t)n * BC + b * 64;
            float xt = 0.f, axt = 0.f;
            if (HASX) {
                xt = xv[((size_t)b * TT + t) * NN + n];
                axt = axv[((size_t)b * TT + t) * NN + n];
            }
#pragma unroll
            for (int nt = 0; nt < NT; ++nt) {
                const int o = ob + nt * 16 + lr;
                float val = OUT[m][nt][r] + bias[nd][nt];
                if (HASX) val += xt * wx[0][nd][nt] + axt * wx[1][nd][nt];
                if (GATE) {
                    const float sg = sigmoidf_(val);
                    if (ob < 64) {
                        zf[nb + o] = sg;
                    } else {
                        outb[nb + (o - 64)] = f2bf(sg * hf[nb + (o - 64)]);
                    }
                } else {
                    const float hc = tanhf(val);
                    const float z = zf[nb + o];
                    const float hn = z * hf[nb + o] + (1.f - z) * hc;
                    outf[nb + o] = hn;
                    outb[nb + o] = f2bf(hn);
                }
            }
        }
    }
}

// ---------------- head: y[b,ot,n] = hb[ot] + sum_h h1[n][b*64+h]*hw[ot,h] ----------------
__global__ __launch_bounds__(256) void head_kernel(const float* __restrict__ h1,
                                                   const float* __restrict__ hw,
                                                   const float* __restrict__ hb,
                                                   float* __restrict__ y) {
    __shared__ float wl[T_OUT * HH];
    const int tid = threadIdx.x;
    for (int idx = tid; idx < T_OUT * HH; idx += 256) wl[idx] = hw[idx];
    __syncthreads();
    const int gi = blockIdx.x * 256 + tid;
    if (gi >= BB * NN) return;
    const int b = gi / NN, n = gi % NN;
    float acc[T_OUT];
#pragma unroll
    for (int ot = 0; ot < T_OUT; ++ot) acc[ot] = hb[ot];
    for (int h = 0; h < HH; ++h) {
        float v = h1[(size_t)n * BC + b * 64 + h];
#pragma unroll
        for (int ot = 0; ot < T_OUT; ++ot) acc[ot] += v * wl[ot * HH + h];
    }
#pragma unroll
    for (int ot = 0; ot < T_OUT; ++ot)
        y[((size_t)b * T_OUT + ot) * NN + n] = acc[ot];
}

extern "C" void kernel_launch(void* const* d_in, const int* in_sizes, int n_in,
                              void* d_out, int out_size, void* d_ws, size_t ws_size,
                              hipStream_t stream) {
    const float* x = (const float*)d_in[0];
    const float* node_emb = (const float*)d_in[1];
    const float* adapt_emb = (const float*)d_in[2];
    const float* Wg0 = (const float*)d_in[3];
    const float* bg0 = (const float*)d_in[4];
    const float* Wc0 = (const float*)d_in[5];
    const float* bc0 = (const float*)d_in[6];
    const float* Wg1 = (const float*)d_in[7];
    const float* bg1 = (const float*)d_in[8];
    const float* Wc1 = (const float*)d_in[9];
    const float* bc1 = (const float*)d_in[10];
    const float* head_w = (const float*)d_in[11];
    const float* head_b = (const float*)d_in[12];
    float* y = (float*)d_out;

    char* ws = (char*)d_ws;
    ushort_t* Abf  = (ushort_t*)(ws + ABF_OFF);
    ushort_t* h1T  = (ushort_t*)(ws + H1T_OFF);
    ushort_t* tmpT = (ushort_t*)(ws + TMPT_OFF);
    float* h0f = (float*)(ws + H0F_OFF);
    float* h1f = (float*)(ws + H1F_OFF);
    float* zf  = (float*)(ws + ZF_OFF);
    ushort_t* h0b = (ushort_t*)(ws + H0B_OFF);
    ushort_t* h1b = (ushort_t*)(ws + H1B_OFF);
    ushort_t* rhb = (ushort_t*)(ws + RHB_OFF);
    ushort_t* Ah0 = (ushort_t*)(ws + AH0_OFF);
    ushort_t* AhX = (ushort_t*)(ws + AHX_OFF);
    float* Axf = (float*)(ws + AXF_OFF);
    ushort_t* Btg0 = (ushort_t*)(ws + BTG0_OFF);
    ushort_t* Btc0 = (ushort_t*)(ws + BTC0_OFF);
    ushort_t* Btg1 = (ushort_t*)(ws + BTG1_OFF);
    ushort_t* Btc1 = (ushort_t*)(ws + BTC1_OFF);
    float* Af32 = zf;  // overlay: consumed before first gate writes z

    hipMemsetAsync(h0f, 0, SZ_ST4, stream);
    hipMemsetAsync(h1f, 0, SZ_ST4, stream);
    hipMemsetAsync(h0b, 0, SZ_ST2, stream);
    hipMemsetAsync(h1b, 0, SZ_ST2, stream);
    hipMemsetAsync(Ah0, 0, SZ_ST2, stream);
    hipMemsetAsync(h1T, 0, SZ_NPNP2, stream);

    // one-time setup
    compute_A_kernel<<<NN, 256, 0, stream>>>(adapt_emb, Af32);
    ax_kernel<<<dim3((NN + 63) / 64, BB), 256, 0, stream>>>(Af32, x, Axf);
    convert_A<<<(NP * NP) / 256, 256, 0, stream>>>(Af32, Abf);
    prepW<65, 128, true><<<(DD * 128 * 128 + 255) / 256, 256, 0, stream>>>(Wg0, Btg0);
    prepW<65, 64, true><<<(DD * 64 * 128 + 255) / 256, 256, 0, stream>>>(Wc0, Btc0);
    prepW<128, 128, false><<<(DD * 128 * 256 + 255) / 256, 256, 0, stream>>>(Wg1, Btg1);
    prepW<128, 64, false><<<(DD * 64 * 256 + 255) / 256, 256, 0, stream>>>(Wc1, Btc1);

    const dim3 gG(NP / 64, NP / 128);  // 32 x 16 = 512 blocks
    const dim3 gT(NP / 64, NP / 64);   // 32 x 32
    const int gN = NN * BB / 64;       // 1000 blocks

    for (int t = 0; t < TT; ++t) {
        // layer0 gate: segs [h0 | A h0] (+x rank-2) -> zf, rhb
        napl2<2, 128, true, true><<<gN, 256, 0, stream>>>(
            Btg0, bg0, node_emb, Wg0, h0b, Ah0, h0b, h0b, x, Axf, h0f, zf, rhb, nullptr, t);
        transpose_bf<<<gT, 256, 0, stream>>>(rhb, tmpT);
        gemm_mfma<<<gG, 256, 0, stream>>>(Abf, tmpT, AhX);  // Arh0
        // layer0 cand: segs [rh | A rh] (+x) -> h0f, h0b
        napl2<2, 64, false, true><<<gN, 256, 0, stream>>>(
            Btc0, bc0, node_emb, Wc0, rhb, AhX, rhb, rhb, x, Axf, h0f, zf, h0b, h0f, t);
        transpose_bf<<<gT, 256, 0, stream>>>(h0b, tmpT);
        gemm_mfma<<<gG, 256, 0, stream>>>(Abf, tmpT, Ah0);  // A h0_new (also next step's gate0)
        gemm_mfma<<<gG, 256, 0, stream>>>(Abf, h1T, AhX);   // A h1_prev
        // layer1 gate: segs [h0new | A h0new | h1 | A h1] -> zf, rhb
        napl2<4, 128, true, false><<<gN, 256, 0, stream>>>(
            Btg1, bg1, node_emb, nullptr, h0b, Ah0, h1b, AhX, nullptr, nullptr, h1f, zf, rhb, nullptr, t);
        transpose_bf<<<gT, 256, 0, stream>>>(rhb, tmpT);
        gemm_mfma<<<gG, 256, 0, stream>>>(Abf, tmpT, AhX);  // Arh1
        // layer1 cand: segs [h0new | A h0new | rh1 | A rh1] -> h1f, h1b
        napl2<4, 64, false, false><<<gN, 256, 0, stream>>>(
            Btc1, bc1, node_emb, nullptr, h0b, Ah0, rhb, AhX, nullptr, nullptr, h1f, zf, h1b, h1f, t);
        transpose_bf<<<gT, 256, 0, stream>>>(h1b, h1T);
    }

    head_kernel<<<(BB * NN + 255) / 256, 256, 0, stream>>>(h1f, head_w, head_b, y);
}